// Round 1
// baseline (2340.885 us; speedup 1.0000x reference)
//
#include <hip/hip_runtime.h>
#include <hip/hip_bf16.h>

#define N_NODES 50000
#define N_EDGES 800000
#define N_GRAPHS 64

// ---------------- small helper kernels ----------------

__global__ void k_fill1(float* __restrict__ d, int n) {
    int i = blockIdx.x * 256 + threadIdx.x;
    if (i < n) d[i] = 1.0f;   // self-loop contributes 1 to every degree
}

__global__ void k_count(const int* __restrict__ ei, float* __restrict__ deg, int E) {
    int e = blockIdx.x * 256 + threadIdx.x;
    if (e < E) unsafeAtomicAdd(&deg[ei[E + e]], 1.0f);   // dst = row 1
}

__global__ void k_rsqrt(float* __restrict__ d, int n) {
    int i = blockIdx.x * 256 + threadIdx.x;
    if (i < n) d[i] = rsqrtf(d[i]);   // deg >= 1 always (self-loop)
}

__global__ void k_norm(const int* __restrict__ ei, const float* __restrict__ dinv,
                       float* __restrict__ nrm, int E) {
    int e = blockIdx.x * 256 + threadIdx.x;
    if (e < E) nrm[e] = dinv[ei[e]] * dinv[ei[E + e]];
}

// qq[g] = relu(qe[g] @ fc0_w + fc0_b) @ fc1_bot + fc1_b   (fc1_bot = fc1_w rows 128..255)
__global__ __launch_bounds__(128) void k_qq(const float* __restrict__ qe,
                                            const float* __restrict__ fc0w,
                                            const float* __restrict__ fc0b,
                                            const float* __restrict__ fc1bot,
                                            const float* __restrict__ fc1b,
                                            float* __restrict__ qq) {
    int g = blockIdx.x, j = threadIdx.x;
    __shared__ float qs[768];
    __shared__ float ql[128];
    for (int i = j; i < 768; i += 128) qs[i] = qe[g * 768 + i];
    __syncthreads();
    float acc = fc0b[j];
    for (int k = 0; k < 768; ++k) acc += qs[k] * fc0w[k * 128 + j];
    ql[j] = fmaxf(acc, 0.0f);
    __syncthreads();
    float acc2 = fc1b[j];
    for (int k = 0; k < 128; ++k) acc2 += ql[k] * fc1bot[k * 128 + j];
    qq[g * 128 + j] = acc2;
}

// agg[dst] += h[src] * norm   (one wave per edge, float2 per lane, HW f32 atomics)
__global__ __launch_bounds__(256) void k_scatter(const float* __restrict__ h,
                                                 const int* __restrict__ ei,
                                                 const float* __restrict__ nrm,
                                                 float* __restrict__ agg, int E) {
    int e = blockIdx.x * 4 + (threadIdx.x >> 6);
    if (e >= E) return;
    int lane = threadIdx.x & 63;
    int s = ei[e];
    int d = ei[E + e];
    float nv = nrm[e];
    const float2 v = ((const float2*)(h + (size_t)s * 128))[lane];
    float* dst = agg + (size_t)d * 128 + 2 * lane;
    unsafeAtomicAdd(dst, v.x * nv);
    unsafeAtomicAdd(dst + 1, v.y * nv);
}

// agg = relu(agg + h*dinv^2 + b)   (self-loop folded in here; 4 floats/thread)
__global__ __launch_bounds__(256) void k_final(float* __restrict__ agg,
                                               const float* __restrict__ h,
                                               const float* __restrict__ dinv,
                                               const float* __restrict__ b, int n) {
    size_t idx = ((size_t)blockIdx.x * 256 + threadIdx.x) * 4;
    if (idx >= (size_t)n * 128) return;
    int node = (int)(idx >> 7);
    int k = (int)(idx & 127);
    float di = dinv[node];
    float s = di * di;
    float4 a = *(const float4*)(agg + idx);
    float4 hv = *(const float4*)(h + idx);
    float4 bb = *(const float4*)(b + k);
    a.x = fmaxf(a.x + hv.x * s + bb.x, 0.0f);
    a.y = fmaxf(a.y + hv.y * s + bb.y, 0.0f);
    a.z = fmaxf(a.z + hv.z * s + bb.z, 0.0f);
    a.w = fmaxf(a.w + hv.w * s + bb.w, 0.0f);
    *(float4*)(agg + idx) = a;
}

// ---------------- fp32 GEMM, K=128, 64x64 tile, 4x4 per thread ----------------
// MODE 0: out = A@W              MODE 1: out = relu(A@W + qq[batch[row]])
template <int MODE>
__global__ __launch_bounds__(256) void gemm64(const float* __restrict__ A,
                                              const float* __restrict__ W,
                                              const float* __restrict__ qq,
                                              const int* __restrict__ batch,
                                              float* __restrict__ out, int nrows) {
    __shared__ float xs[64][132];   // +4 pad: rows 4 apart hit distinct banks
    __shared__ float ws[128][64];
    const int tid = threadIdx.x;
    const int row0 = blockIdx.x * 64;
    const int col0 = blockIdx.y * 64;

    #pragma unroll
    for (int i = 0; i < 8; ++i) {                 // stage A tile: 2048 float4
        int flat = i * 256 + tid;
        int r = flat >> 5, c4 = flat & 31;
        int gr = row0 + r;
        float4 v = make_float4(0.f, 0.f, 0.f, 0.f);
        if (gr < nrows) v = ((const float4*)(A + (size_t)gr * 128))[c4];
        *((float4*)&xs[r][0] + c4) = v;
    }
    #pragma unroll
    for (int i = 0; i < 8; ++i) {                 // stage W tile (64 cols)
        int flat = i * 256 + tid;
        int k = flat >> 4, c4 = flat & 15;
        *((float4*)&ws[k][0] + c4) = ((const float4*)(W + (size_t)k * 128 + col0))[c4];
    }
    __syncthreads();

    const int tc = tid & 15;    // 16 col groups * 4
    const int tr = tid >> 4;    // 16 row groups * 4
    float acc[4][4] = {};
    for (int k = 0; k < 128; k += 4) {
        float av[4][4], wv[4][4];
        #pragma unroll
        for (int r = 0; r < 4; ++r) *(float4*)av[r] = *(const float4*)&xs[tr * 4 + r][k];
        #pragma unroll
        for (int kk = 0; kk < 4; ++kk) *(float4*)wv[kk] = *(const float4*)&ws[k + kk][tc * 4];
        #pragma unroll
        for (int r = 0; r < 4; ++r)
            #pragma unroll
            for (int c = 0; c < 4; ++c)
                #pragma unroll
                for (int kk = 0; kk < 4; ++kk)
                    acc[r][c] += av[r][kk] * wv[kk][c];
    }

    #pragma unroll
    for (int r = 0; r < 4; ++r) {
        int gr = row0 + tr * 4 + r;
        if (gr >= nrows) continue;
        float4 v;
        if (MODE == 1) {
            int g = batch[gr];
            const float4 qv = *(const float4*)(qq + (size_t)g * 128 + col0 + tc * 4);
            v.x = fmaxf(acc[r][0] + qv.x, 0.f);
            v.y = fmaxf(acc[r][1] + qv.y, 0.f);
            v.z = fmaxf(acc[r][2] + qv.z, 0.f);
            v.w = fmaxf(acc[r][3] + qv.w, 0.f);
        } else {
            v = make_float4(acc[r][0], acc[r][1], acc[r][2], acc[r][3]);
        }
        *(float4*)(out + (size_t)gr * 128 + col0 + tc * 4) = v;
    }
}

// ---------------- fc2: [N,128] @ [128,32] + b ----------------
__global__ __launch_bounds__(128) void gemm32(const float* __restrict__ A,
                                              const float* __restrict__ W,
                                              const float* __restrict__ bias,
                                              float* __restrict__ out, int nrows) {
    __shared__ float xs[64][132];
    __shared__ float ws[128][32];
    const int tid = threadIdx.x;
    const int row0 = blockIdx.x * 64;

    #pragma unroll
    for (int i = 0; i < 16; ++i) {
        int flat = i * 128 + tid;
        int r = flat >> 5, c4 = flat & 31;
        int gr = row0 + r;
        float4 v = make_float4(0.f, 0.f, 0.f, 0.f);
        if (gr < nrows) v = ((const float4*)(A + (size_t)gr * 128))[c4];
        *((float4*)&xs[r][0] + c4) = v;
    }
    #pragma unroll
    for (int i = 0; i < 8; ++i) {
        int flat = i * 128 + tid;
        int k = flat >> 3, c4 = flat & 7;
        *((float4*)&ws[k][0] + c4) = ((const float4*)(W + (size_t)k * 32))[c4];
    }
    __syncthreads();

    const int tc = tid & 7;    // 8 col groups * 4 = 32 cols
    const int tr = tid >> 3;   // 16 row groups * 4 = 64 rows
    float acc[4][4] = {};
    for (int k = 0; k < 128; k += 4) {
        float av[4][4], wv[4][4];
        #pragma unroll
        for (int r = 0; r < 4; ++r) *(float4*)av[r] = *(const float4*)&xs[tr * 4 + r][k];
        #pragma unroll
        for (int kk = 0; kk < 4; ++kk) *(float4*)wv[kk] = *(const float4*)&ws[k + kk][tc * 4];
        #pragma unroll
        for (int r = 0; r < 4; ++r)
            #pragma unroll
            for (int c = 0; c < 4; ++c)
                #pragma unroll
                for (int kk = 0; kk < 4; ++kk)
                    acc[r][c] += av[r][kk] * wv[kk][c];
    }

    const float4 bb = *(const float4*)(bias + tc * 4);
    #pragma unroll
    for (int r = 0; r < 4; ++r) {
        int gr = row0 + tr * 4 + r;
        if (gr >= nrows) continue;
        float4 v = make_float4(acc[r][0] + bb.x, acc[r][1] + bb.y,
                               acc[r][2] + bb.z, acc[r][3] + bb.w);
        *(float4*)(out + (size_t)gr * 32 + tc * 4) = v;
    }
}

// ---------------- launch ----------------

extern "C" void kernel_launch(void* const* d_in, const int* in_sizes, int n_in,
                              void* d_out, int out_size, void* d_ws, size_t ws_size,
                              hipStream_t stream) {
    const float* x    = (const float*)d_in[0];
    const int*   ei   = (const int*)d_in[1];
    const int*   batch= (const int*)d_in[2];
    const float* qe   = (const float*)d_in[3];
    const float* W0   = (const float*)d_in[4];
    const float* b0   = (const float*)d_in[5];
    const float* W1   = (const float*)d_in[6];
    const float* b1   = (const float*)d_in[7];
    const float* W2   = (const float*)d_in[8];
    const float* b2   = (const float*)d_in[9];
    const float* fc0w = (const float*)d_in[10];
    const float* fc0b = (const float*)d_in[11];
    const float* fc1w = (const float*)d_in[12];
    const float* fc1b = (const float*)d_in[13];
    const float* fc2w = (const float*)d_in[14];
    const float* fc2b = (const float*)d_in[15];
    float* out = (float*)d_out;

    float* WS   = (float*)d_ws;
    float* H    = WS;                       // [50000,128]
    float* AGG  = WS + 6400000;             // [50000,128]
    float* DINV = WS + 12800000;            // [50000]
    float* NORM = DINV + 50000;             // [800000]
    float* QQ   = NORM + 800000;            // [64,128]

    const int N = N_NODES, E = N_EDGES;
    const int nb  = (N + 255) / 256;        // 196
    const int eb  = (E + 255) / 256;        // 3125
    const dim3 gg((N + 63) / 64, 2);        // (782,2)
    const size_t featBytes = (size_t)N * 128 * sizeof(float);

    // normalization
    k_fill1<<<nb, 256, 0, stream>>>(DINV, N);
    k_count<<<eb, 256, 0, stream>>>(ei, DINV, E);
    k_rsqrt<<<nb, 256, 0, stream>>>(DINV, N);
    k_norm <<<eb, 256, 0, stream>>>(ei, DINV, NORM, E);

    // question path: qq = relu(qe@fc0+b)@fc1_bot + fc1_b
    k_qq<<<N_GRAPHS, 128, 0, stream>>>(qe, fc0w, fc0b, fc1w + 128 * 128, fc1b, QQ);

    // layer 1
    gemm64<0><<<gg, 256, 0, stream>>>(x, W0, nullptr, nullptr, H, N);
    hipMemsetAsync(AGG, 0, featBytes, stream);
    k_scatter<<<(E + 3) / 4, 256, 0, stream>>>(H, ei, NORM, AGG, E);
    k_final<<<(N * 128 / 4 + 255) / 256, 256, 0, stream>>>(AGG, H, DINV, b0, N);
    // layer 2
    gemm64<0><<<gg, 256, 0, stream>>>(AGG, W1, nullptr, nullptr, H, N);
    hipMemsetAsync(AGG, 0, featBytes, stream);
    k_scatter<<<(E + 3) / 4, 256, 0, stream>>>(H, ei, NORM, AGG, E);
    k_final<<<(N * 128 / 4 + 255) / 256, 256, 0, stream>>>(AGG, H, DINV, b1, N);
    // layer 3
    gemm64<0><<<gg, 256, 0, stream>>>(AGG, W2, nullptr, nullptr, H, N);
    hipMemsetAsync(AGG, 0, featBytes, stream);
    k_scatter<<<(E + 3) / 4, 256, 0, stream>>>(H, ei, NORM, AGG, E);
    k_final<<<(N * 128 / 4 + 255) / 256, 256, 0, stream>>>(AGG, H, DINV, b2, N);

    // fc1 (concat folded: h3 @ fc1_top + qq[batch], relu)
    gemm64<1><<<gg, 256, 0, stream>>>(AGG, fc1w, QQ, batch, H, N);
    // fc2 -> d_out
    gemm32<<<(N + 63) / 64, 128, 0, stream>>>(H, fc2w, fc2b, out, N);
}

// Round 2
// 519.552 us; speedup vs baseline: 4.5056x; 4.5056x over previous
//
#include <hip/hip_runtime.h>
#include <hip/hip_bf16.h>

#define N_NODES 50000
#define N_EDGES 800000
#define N_GRAPHS 64

// ---------------- degree / normalization ----------------

__global__ void k_hist(const int* __restrict__ ei, int* __restrict__ cnt, int E) {
    int e = blockIdx.x * 256 + threadIdx.x;
    if (e < E) atomicAdd(&cnt[ei[E + e]], 1);   // in-degree (dst = row 1)
}

__global__ void k_dinv(const int* __restrict__ cnt, float* __restrict__ dinv, int n) {
    int i = blockIdx.x * 256 + threadIdx.x;
    if (i < n) dinv[i] = rsqrtf((float)(cnt[i] + 1));   // +1 self-loop
}

// ---------------- exclusive scan (3-phase) ----------------

__global__ __launch_bounds__(512) void k_scan_a(const int* __restrict__ cnt,
                                                int* __restrict__ rowptr,
                                                int* __restrict__ bsum, int n) {
    __shared__ int s[512];
    int t = threadIdx.x;
    int i = blockIdx.x * 512 + t;
    int v = (i < n) ? cnt[i] : 0;
    s[t] = v;
    __syncthreads();
    for (int d = 1; d < 512; d <<= 1) {
        int x = (t >= d) ? s[t - d] : 0;
        __syncthreads();
        s[t] += x;
        __syncthreads();
    }
    if (i < n) rowptr[i] = s[t] - v;             // exclusive within block
    if (t == 511) bsum[blockIdx.x] = s[511];
}

__global__ __launch_bounds__(128) void k_scan_b(int* __restrict__ bsum, int nb) {
    __shared__ int s[128];
    int t = threadIdx.x;
    int v = (t < nb) ? bsum[t] : 0;
    s[t] = v;
    __syncthreads();
    for (int d = 1; d < 128; d <<= 1) {
        int x = (t >= d) ? s[t - d] : 0;
        __syncthreads();
        s[t] += x;
        __syncthreads();
    }
    if (t < nb) bsum[t] = s[t] - v;
}

__global__ __launch_bounds__(512) void k_scan_c(int* __restrict__ rowptr,
                                                const int* __restrict__ bsum,
                                                int n, int E) {
    int i = blockIdx.x * 512 + threadIdx.x;
    if (i < n) rowptr[i] += bsum[blockIdx.x];
    if (i == 0) rowptr[n] = E;
}

// ---------------- CSR fill (bucket edges by dst) ----------------

__global__ void k_fill_csr(const int* __restrict__ ei, const int* __restrict__ rowptr,
                           int* __restrict__ fill, int* __restrict__ colA, int E) {
    int e = blockIdx.x * 256 + threadIdx.x;
    if (e >= E) return;
    int s = ei[e], d = ei[E + e];
    int pos = rowptr[d] + atomicAdd(&fill[d], 1);
    colA[pos] = s;
}

// ---------------- question path ----------------
// qq[g] = relu(qe[g] @ fc0_w + fc0_b) @ fc1_bot + fc1_b   (fc1_bot = fc1_w rows 128..255)
__global__ __launch_bounds__(128) void k_qq(const float* __restrict__ qe,
                                            const float* __restrict__ fc0w,
                                            const float* __restrict__ fc0b,
                                            const float* __restrict__ fc1bot,
                                            const float* __restrict__ fc1b,
                                            float* __restrict__ qq) {
    int g = blockIdx.x, j = threadIdx.x;
    __shared__ float qs[768];
    __shared__ float ql[128];
    for (int i = j; i < 768; i += 128) qs[i] = qe[g * 768 + i];
    __syncthreads();
    float acc = fc0b[j];
    for (int k = 0; k < 768; ++k) acc += qs[k] * fc0w[k * 128 + j];
    ql[j] = fmaxf(acc, 0.0f);
    __syncthreads();
    float acc2 = fc1b[j];
    for (int k = 0; k < 128; ++k) acc2 += ql[k] * fc1bot[k * 128 + j];
    qq[g * 128 + j] = acc2;
}

// ---------------- CSR gather aggregation (fused self-loop + bias + relu) ----------------
// One wave per node; lane handles 2 features (float2). Wave-uniform edge loop ->
// col/dinv loads scalarize; exactly one global_load_dwordx2 per lane per edge.
__global__ __launch_bounds__(256) void k_gather(const float* __restrict__ h,
                                                const int* __restrict__ rowptr,
                                                const int* __restrict__ colA,
                                                const float* __restrict__ dinv,
                                                const float* __restrict__ bias,
                                                float* __restrict__ outp, int n) {
    int node = __builtin_amdgcn_readfirstlane(blockIdx.x * 4 + (threadIdx.x >> 6));
    if (node >= n) return;
    int lane = threadIdx.x & 63;
    int e0 = rowptr[node], e1 = rowptr[node + 1];
    float di = dinv[node];
    float accx = 0.f, accy = 0.f;
    int e = e0;
    for (; e + 4 <= e1; e += 4) {                 // 4 outstanding gathers
        int s0 = colA[e], s1 = colA[e + 1], s2 = colA[e + 2], s3 = colA[e + 3];
        float2 v0 = ((const float2*)(h + (size_t)s0 * 128))[lane];
        float2 v1 = ((const float2*)(h + (size_t)s1 * 128))[lane];
        float2 v2 = ((const float2*)(h + (size_t)s2 * 128))[lane];
        float2 v3 = ((const float2*)(h + (size_t)s3 * 128))[lane];
        float w0 = dinv[s0] * di, w1 = dinv[s1] * di;
        float w2 = dinv[s2] * di, w3 = dinv[s3] * di;
        accx += v0.x * w0 + v1.x * w1 + v2.x * w2 + v3.x * w3;
        accy += v0.y * w0 + v1.y * w1 + v2.y * w2 + v3.y * w3;
    }
    for (; e < e1; ++e) {
        int s = colA[e];
        float w = dinv[s] * di;
        float2 v = ((const float2*)(h + (size_t)s * 128))[lane];
        accx += v.x * w;
        accy += v.y * w;
    }
    float sw = di * di;                            // self-loop weight
    float2 hv = ((const float2*)(h + (size_t)node * 128))[lane];
    float2 bb = ((const float2*)bias)[lane];
    float2 o;
    o.x = fmaxf(accx + hv.x * sw + bb.x, 0.f);
    o.y = fmaxf(accy + hv.y * sw + bb.y, 0.f);
    ((float2*)(outp + (size_t)node * 128))[lane] = o;
}

// ---------------- fp32 GEMM, K=128, 64x64 tile, 4x4 per thread ----------------
// MODE 0: out = A@W              MODE 1: out = relu(A@W + qq[batch[row]])
template <int MODE>
__global__ __launch_bounds__(256) void gemm64(const float* __restrict__ A,
                                              const float* __restrict__ W,
                                              const float* __restrict__ qq,
                                              const int* __restrict__ batch,
                                              float* __restrict__ out, int nrows) {
    __shared__ float xs[64][132];
    __shared__ float ws[128][64];
    const int tid = threadIdx.x;
    const int row0 = blockIdx.x * 64;
    const int col0 = blockIdx.y * 64;

    #pragma unroll
    for (int i = 0; i < 8; ++i) {
        int flat = i * 256 + tid;
        int r = flat >> 5, c4 = flat & 31;
        int gr = row0 + r;
        float4 v = make_float4(0.f, 0.f, 0.f, 0.f);
        if (gr < nrows) v = ((const float4*)(A + (size_t)gr * 128))[c4];
        *((float4*)&xs[r][0] + c4) = v;
    }
    #pragma unroll
    for (int i = 0; i < 8; ++i) {
        int flat = i * 256 + tid;
        int k = flat >> 4, c4 = flat & 15;
        *((float4*)&ws[k][0] + c4) = ((const float4*)(W + (size_t)k * 128 + col0))[c4];
    }
    __syncthreads();

    const int tc = tid & 15;
    const int tr = tid >> 4;
    float acc[4][4] = {};
    for (int k = 0; k < 128; k += 4) {
        float av[4][4], wv[4][4];
        #pragma unroll
        for (int r = 0; r < 4; ++r) *(float4*)av[r] = *(const float4*)&xs[tr * 4 + r][k];
        #pragma unroll
        for (int kk = 0; kk < 4; ++kk) *(float4*)wv[kk] = *(const float4*)&ws[k + kk][tc * 4];
        #pragma unroll
        for (int r = 0; r < 4; ++r)
            #pragma unroll
            for (int c = 0; c < 4; ++c)
                #pragma unroll
                for (int kk = 0; kk < 4; ++kk)
                    acc[r][c] += av[r][kk] * wv[kk][c];
    }

    #pragma unroll
    for (int r = 0; r < 4; ++r) {
        int gr = row0 + tr * 4 + r;
        if (gr >= nrows) continue;
        float4 v;
        if (MODE == 1) {
            int g = batch[gr];
            const float4 qv = *(const float4*)(qq + (size_t)g * 128 + col0 + tc * 4);
            v.x = fmaxf(acc[r][0] + qv.x, 0.f);
            v.y = fmaxf(acc[r][1] + qv.y, 0.f);
            v.z = fmaxf(acc[r][2] + qv.z, 0.f);
            v.w = fmaxf(acc[r][3] + qv.w, 0.f);
        } else {
            v = make_float4(acc[r][0], acc[r][1], acc[r][2], acc[r][3]);
        }
        *(float4*)(out + (size_t)gr * 128 + col0 + tc * 4) = v;
    }
}

// ---------------- fc2: [N,128] @ [128,32] + b ----------------
__global__ __launch_bounds__(128) void gemm32(const float* __restrict__ A,
                                              const float* __restrict__ W,
                                              const float* __restrict__ bias,
                                              float* __restrict__ out, int nrows) {
    __shared__ float xs[64][132];
    __shared__ float ws[128][32];
    const int tid = threadIdx.x;
    const int row0 = blockIdx.x * 64;

    #pragma unroll
    for (int i = 0; i < 16; ++i) {
        int flat = i * 128 + tid;
        int r = flat >> 5, c4 = flat & 31;
        int gr = row0 + r;
        float4 v = make_float4(0.f, 0.f, 0.f, 0.f);
        if (gr < nrows) v = ((const float4*)(A + (size_t)gr * 128))[c4];
        *((float4*)&xs[r][0] + c4) = v;
    }
    #pragma unroll
    for (int i = 0; i < 8; ++i) {
        int flat = i * 128 + tid;
        int k = flat >> 3, c4 = flat & 7;
        *((float4*)&ws[k][0] + c4) = ((const float4*)(W + (size_t)k * 32))[c4];
    }
    __syncthreads();

    const int tc = tid & 7;
    const int tr = tid >> 3;
    float acc[4][4] = {};
    for (int k = 0; k < 128; k += 4) {
        float av[4][4], wv[4][4];
        #pragma unroll
        for (int r = 0; r < 4; ++r) *(float4*)av[r] = *(const float4*)&xs[tr * 4 + r][k];
        #pragma unroll
        for (int kk = 0; kk < 4; ++kk) *(float4*)wv[kk] = *(const float4*)&ws[k + kk][tc * 4];
        #pragma unroll
        for (int r = 0; r < 4; ++r)
            #pragma unroll
            for (int c = 0; c < 4; ++c)
                #pragma unroll
                for (int kk = 0; kk < 4; ++kk)
                    acc[r][c] += av[r][kk] * wv[kk][c];
    }

    const float4 bb = *(const float4*)(bias + tc * 4);
    #pragma unroll
    for (int r = 0; r < 4; ++r) {
        int gr = row0 + tr * 4 + r;
        if (gr >= nrows) continue;
        float4 v = make_float4(acc[r][0] + bb.x, acc[r][1] + bb.y,
                               acc[r][2] + bb.z, acc[r][3] + bb.w);
        *(float4*)(out + (size_t)gr * 32 + tc * 4) = v;
    }
}

// ---------------- launch ----------------

extern "C" void kernel_launch(void* const* d_in, const int* in_sizes, int n_in,
                              void* d_out, int out_size, void* d_ws, size_t ws_size,
                              hipStream_t stream) {
    const float* x    = (const float*)d_in[0];
    const int*   ei   = (const int*)d_in[1];
    const int*   batch= (const int*)d_in[2];
    const float* qe   = (const float*)d_in[3];
    const float* W0   = (const float*)d_in[4];
    const float* b0   = (const float*)d_in[5];
    const float* W1   = (const float*)d_in[6];
    const float* b1   = (const float*)d_in[7];
    const float* W2   = (const float*)d_in[8];
    const float* b2   = (const float*)d_in[9];
    const float* fc0w = (const float*)d_in[10];
    const float* fc0b = (const float*)d_in[11];
    const float* fc1w = (const float*)d_in[12];
    const float* fc1b = (const float*)d_in[13];
    const float* fc2w = (const float*)d_in[14];
    const float* fc2b = (const float*)d_in[15];
    float* out = (float*)d_out;

    float* WS   = (float*)d_ws;
    float* H    = WS;                        // [50000,128]
    float* G    = WS + 6400000;              // [50000,128]
    float* DINV = WS + 12800000;             // [50000]
    float* QQ   = DINV + 50000;              // [64,128]
    int*   CNT  = (int*)(QQ + 8192);         // [50000]  (reused as fill)
    int*   ROWPTR = CNT + 50000;             // [50001] (+pad)
    int*   COL  = ROWPTR + 50008;            // [800000]
    int*   BSUM = COL + 800000;              // [128]

    const int N = N_NODES, E = N_EDGES;
    const int nb  = (N + 255) / 256;         // 196
    const int eb  = (E + 255) / 256;         // 3125
    const int sb  = (N + 511) / 512;         // 98
    const dim3 gg((N + 63) / 64, 2);         // (782,2)

    // ---- CSR build + normalization ----
    hipMemsetAsync(CNT, 0, N * sizeof(int), stream);
    k_hist<<<eb, 256, 0, stream>>>(ei, CNT, E);
    k_dinv<<<nb, 256, 0, stream>>>(CNT, DINV, N);
    k_scan_a<<<sb, 512, 0, stream>>>(CNT, ROWPTR, BSUM, N);
    k_scan_b<<<1, 128, 0, stream>>>(BSUM, sb);
    k_scan_c<<<sb, 512, 0, stream>>>(ROWPTR, BSUM, N, E);
    hipMemsetAsync(CNT, 0, N * sizeof(int), stream);   // reuse as fill counters
    k_fill_csr<<<eb, 256, 0, stream>>>(ei, ROWPTR, CNT, COL, E);

    // ---- question path ----
    k_qq<<<N_GRAPHS, 128, 0, stream>>>(qe, fc0w, fc0b, fc1w + 128 * 128, fc1b, QQ);

    // ---- GCN layers: gemm -> csr gather (fused self-loop+bias+relu) ----
    gemm64<0><<<gg, 256, 0, stream>>>(x, W0, nullptr, nullptr, H, N);
    k_gather<<<(N + 3) / 4, 256, 0, stream>>>(H, ROWPTR, COL, DINV, b0, G, N);

    gemm64<0><<<gg, 256, 0, stream>>>(G, W1, nullptr, nullptr, H, N);
    k_gather<<<(N + 3) / 4, 256, 0, stream>>>(H, ROWPTR, COL, DINV, b1, G, N);

    gemm64<0><<<gg, 256, 0, stream>>>(G, W2, nullptr, nullptr, H, N);
    k_gather<<<(N + 3) / 4, 256, 0, stream>>>(H, ROWPTR, COL, DINV, b2, G, N);

    // ---- fc1 (concat folded: h3 @ fc1_top + qq[batch], relu) ----
    gemm64<1><<<gg, 256, 0, stream>>>(G, fc1w, QQ, batch, H, N);
    // ---- fc2 -> d_out ----
    gemm32<<<(N + 63) / 64, 128, 0, stream>>>(H, fc2w, fc2b, out, N);
}